// Round 11
// baseline (251.389 us; speedup 1.0000x reference)
//
#include <hip/hip_runtime.h>
#include <cstdint>

// ---------------------------------------------------------------------------
// AttentionBlock: B=2, C=512, H=W=64 (S=4096), 8 heads x 64 dim.
// I/O dtype: fp32. Internal: bf16 MFMA (16x16x32), fp32 accum.
// R10: non-attn wall (~130 us) is dominated by inter-kernel gaps (invariant
// across all GEMM changes; kernel pipe-floors sum to ~30 us). Cut 6 kernels
// to 4: (1) prep = transpose + weight-cvt in one launch; (2) gemm_out absorbs
// attn_combine (A-operand staged via manual load of partials + in-register
// (a0+a1)/(l0+l1) + ds_write_b128, same LDS layout as the DMA path).
// attn128 / gemm_qkv unchanged from the R9-passing version.
// B^T-form MFMA: C[m][n] += A[m][k]*B[n][k]; C/D col(n)=lane&15, row(m)=lq*4+reg;
// A/B frag: row=lane&15, k=lq*8+j  (lq = lane>>4).
// ---------------------------------------------------------------------------

typedef __bf16 bf16x8 __attribute__((ext_vector_type(8)));
typedef __bf16 bf16x4 __attribute__((ext_vector_type(4)));
typedef float f32x4 __attribute__((ext_vector_type(4)));
typedef unsigned short u16x8 __attribute__((ext_vector_type(8)));
typedef unsigned short u16x4 __attribute__((ext_vector_type(4)));

#define AS1 __attribute__((address_space(1)))
#define AS3 __attribute__((address_space(3)))

__device__ __forceinline__ void async16(const void* g, void* l) {
  __builtin_amdgcn_global_load_lds((const AS1 void*)g, (AS3 void*)l, 16, 0, 0);
}

__device__ __forceinline__ uint16_t f2bf(float f) {
  union { float f; uint32_t u; } a;
  a.f = f;
  uint32_t r = a.u + 0x7fffu + ((a.u >> 16) & 1u);  // RNE
  return (uint16_t)(r >> 16);
}

__device__ __forceinline__ float bf2f(uint16_t u) {
  union { uint32_t u; float f; } a;
  a.u = (uint32_t)u << 16;
  return a.f;
}

// ---------------------------------------------------------------------------
// prep: z=0..3 -> transpose+convert x/ctx [C][S] fp32 -> [S][C] bf16;
//       z=4    -> convert the 4 weight matrices fp32 -> bf16 (flat).
// grid (64, 8, 5), block 256.
// ---------------------------------------------------------------------------
__global__ __launch_bounds__(256) void prep(
    const float* __restrict__ x, const float* __restrict__ ctx,
    const float* __restrict__ Wq, const float* __restrict__ Wk,
    const float* __restrict__ Wv, const float* __restrict__ Wo,
    uint16_t* __restrict__ xT, uint16_t* __restrict__ cT,
    uint16_t* __restrict__ Wqb, uint16_t* __restrict__ Wkb,
    uint16_t* __restrict__ Wvb, uint16_t* __restrict__ Wob) {
  const int zz = blockIdx.z;
  const int t = threadIdx.x;
  if (zz == 4) {
    const float* W[4] = {Wq, Wk, Wv, Wo};
    uint16_t* O[4] = {Wqb, Wkb, Wvb, Wob};
    const int blk = blockIdx.x + 64 * blockIdx.y;      // 0..511
    const size_t base = (size_t)blk * 2048 + (size_t)t * 8;
    const int w = (int)(base >> 18);                   // 512*512 = 2^18
    const size_t off = base & 262143;
    float4 v0 = *(const float4*)&W[w][off];
    float4 v1 = *(const float4*)&W[w][off + 4];
    u16x8 o = {f2bf(v0.x), f2bf(v0.y), f2bf(v0.z), f2bf(v0.w),
               f2bf(v1.x), f2bf(v1.y), f2bf(v1.z), f2bf(v1.w)};
    *(u16x8*)&O[w][off] = o;
    return;
  }
  const float* src = (zz < 2 ? x : ctx) + (size_t)(zz & 1) * 512 * 4096;
  uint16_t* dst = (zz < 2 ? xT : cT) + (size_t)(zz & 1) * 4096 * 512;
  const int s0 = blockIdx.x * 64, c0 = blockIdx.y * 64;
  __shared__ uint16_t tile[64][80];
  for (int p = 0; p < 2; ++p) {
    int u = p * 256 + t;
    int r = u >> 3, cg = (u & 7) * 8;
    const float* sp = &src[(size_t)(c0 + r) * 4096 + s0 + cg];
    float4 v0 = *(const float4*)sp;
    float4 v1 = *(const float4*)(sp + 4);
    u16x8 o = {f2bf(v0.x), f2bf(v0.y), f2bf(v0.z), f2bf(v0.w),
               f2bf(v1.x), f2bf(v1.y), f2bf(v1.z), f2bf(v1.w)};
    *(u16x8*)&tile[r][cg] = o;
  }
  __syncthreads();
  for (int p = 0; p < 2; ++p) {
    int u = p * 256 + t;
    int sr = u >> 3, cg = (u & 7) * 8;
    u16x8 v;
    for (int j = 0; j < 8; ++j) v[j] = tile[cg + j][sr];
    *(u16x8*)&dst[(size_t)(s0 + sr) * 512 + c0 + cg] = v;
  }
}

// ---------------------------------------------------------------------------
// Fused QKV projection (unchanged from R9-passing). blockIdx.z = sel*2+batch.
// C[m][n] = (sum_k A[m][k]*B[n][k] + bias) * os, stored C[col*ldC + row].
// Q/K: A=W (m=e), B=xT/cT (n=s), out Q[s][e], bias by row, Q scaled.
// V:   A=cT (m=s), B=Wv (n=e), out Vt[e][s], bias by col.
// ---------------------------------------------------------------------------
struct QkvArgs {
  const uint16_t* A[3]; long long sA[3];
  const uint16_t* B[3]; long long sB[3];
  uint16_t* C[3];       long long sC[3];
  const float* bias[3];
  float os[3];
  long long ldC[3]; int lx[3]; int brow[3];
};

__global__ __launch_bounds__(256) void gemm_qkv(QkvArgs ga) {
  constexpr int K = 512;
  __shared__ uint16_t At[128 * 32];
  __shared__ uint16_t Bt[128 * 32];
  const int t = threadIdx.x, lane = t & 63, wave = t >> 6;
  const int lr = lane & 15, lq = lane >> 4;
  const int wm = (wave >> 1) * 64, wn = (wave & 1) * 64;
  const int sel = blockIdx.z >> 1, bat = blockIdx.z & 1;
  const int lx = ga.lx[sel], brow = ga.brow[sel];
  const long long ldC = ga.ldC[sel];
  const float os = ga.os[sel];
  const int n0 = (blockIdx.x & ((1 << lx) - 1)) * 128;
  const int m0 = (blockIdx.x >> lx) * 128;
  const uint16_t* A = ga.A[sel] + (size_t)bat * ga.sA[sel];
  const uint16_t* B = ga.B[sel] + (size_t)bat * ga.sB[sel];
  const float* bias = ga.bias[sel];
  f32x4 acc[4][4] = {};
  for (int k0 = 0; k0 < K; k0 += 32) {
    __syncthreads();
    for (int p = 0; p < 2; ++p) {
      int u = p * 256 + t;
      int r = u >> 2, c = (u & 3) * 8;
      async16(&A[(size_t)(m0 + r) * K + k0 + c], &At[p * 2048 + wave * 512]);
      async16(&B[(size_t)(n0 + r) * K + k0 + c], &Bt[p * 2048 + wave * 512]);
    }
    __builtin_amdgcn_s_waitcnt(0);
    __syncthreads();
    bf16x8 af[4], bfr[4];
    for (int i = 0; i < 4; ++i)
      af[i] = *(const bf16x8*)&At[(wm + i * 16 + lr) * 32 + lq * 8];
    for (int j = 0; j < 4; ++j)
      bfr[j] = *(const bf16x8*)&Bt[(wn + j * 16 + lr) * 32 + lq * 8];
    for (int i = 0; i < 4; ++i)
      for (int j = 0; j < 4; ++j)
        acc[i][j] = __builtin_amdgcn_mfma_f32_16x16x32_bf16(af[i], bfr[j], acc[i][j], 0, 0, 0);
  }
  uint16_t* C = ga.C[sel] + (size_t)bat * ga.sC[sel];
  for (int i = 0; i < 4; ++i)
    for (int j = 0; j < 4; ++j) {
      int row = m0 + wm + i * 16 + lq * 4;
      int col = n0 + wn + j * 16 + lr;
      float bc = brow ? 0.f : bias[col];
      u16x4 o;
      for (int r = 0; r < 4; ++r) {
        float val = (acc[i][j][r] + (brow ? bias[row + r] : bc)) * os;
        o[r] = f2bf(val);
      }
      *(u16x4*)&C[(size_t)col * ldC + row] = o;
    }
}

// ---------------------------------------------------------------------------
// Output projection with FUSED combine. A = (Ap[0]+Ap[1])/(l0+l1) built
// in-register during staging (manual loads + ds_write_b128, same LDS layout
// as the DMA path). B = Wo via async16. m/n-swapped: m=s contiguous ->
// float4 stores into Y[c][s]. 128(m)x64(n) tiles, grid (8, 32, 2).
// ---------------------------------------------------------------------------
__global__ __launch_bounds__(256) void gemm_out(
    const uint16_t* __restrict__ Ap, const float* __restrict__ Lp,
    const uint16_t* __restrict__ Wo, float* __restrict__ Y,
    const float* __restrict__ bias) {
  constexpr int K = 512, S = 4096, E = 512;
  __shared__ uint16_t At[128 * 32];
  __shared__ uint16_t Bt[64 * 32];
  const int t = threadIdx.x, lane = t & 63, wave = t >> 6;
  const int lr = lane & 15, lq = lane >> 4;
  const int wm = (wave & 1) * 64, wn = (wave >> 1) * 32;
  const int m0 = blockIdx.y * 128, n0 = blockIdx.x * 64;
  const int b = blockIdx.z;
  const size_t bOff = (size_t)b * S * E;
  const size_t HALF = (size_t)2 * S * E;  // jh stride in Ap
  f32x4 acc[4][2] = {};
  for (int k0 = 0; k0 < K; k0 += 32) {
    const int h = k0 >> 6;  // head is uniform within a 32-wide k-chunk
    const float* l0p = &Lp[((size_t)b * 8 + h) * S];
    const float* l1p = &Lp[((size_t)(2 + b) * 8 + h) * S];
    __syncthreads();
    for (int p = 0; p < 2; ++p) {
      int u = p * 256 + t;
      int r = u >> 2, c = (u & 3) * 8;
      size_t off = bOff + (size_t)(m0 + r) * E + k0 + c;
      u16x4 a00 = *(const u16x4*)&Ap[off];
      u16x4 a01 = *(const u16x4*)&Ap[off + 4];
      u16x4 a10 = *(const u16x4*)&Ap[HALF + off];
      u16x4 a11 = *(const u16x4*)&Ap[HALF + off + 4];
      float inv = 1.f / (l0p[m0 + r] + l1p[m0 + r]);
      u16x8 o;
      for (int q = 0; q < 4; ++q) {
        o[q]     = f2bf((bf2f(a00[q]) + bf2f(a10[q])) * inv);
        o[q + 4] = f2bf((bf2f(a01[q]) + bf2f(a11[q])) * inv);
      }
      *(u16x8*)&At[r * 32 + c] = o;
    }
    {
      int r = t >> 2, c = (t & 3) * 8;
      async16(&Wo[(size_t)(n0 + r) * K + k0 + c], &Bt[wave * 512]);
    }
    __builtin_amdgcn_s_waitcnt(0);
    __syncthreads();
    bf16x8 af[4], bfr[2];
    for (int i = 0; i < 4; ++i)
      af[i] = *(const bf16x8*)&At[(wm + i * 16 + lr) * 32 + lq * 8];
    for (int j = 0; j < 2; ++j)
      bfr[j] = *(const bf16x8*)&Bt[(wn + j * 16 + lr) * 32 + lq * 8];
    for (int i = 0; i < 4; ++i)
      for (int j = 0; j < 2; ++j)
        acc[i][j] = __builtin_amdgcn_mfma_f32_16x16x32_bf16(af[i], bfr[j], acc[i][j], 0, 0, 0);
  }
  float* Cf = Y + (size_t)b * 512 * 4096;
  for (int i = 0; i < 4; ++i)
    for (int j = 0; j < 2; ++j) {
      int row = m0 + wm + i * 16 + lq * 4;  // s (contiguous)
      int col = n0 + wn + j * 16 + lr;      // c
      float bb = bias[col];
      float4 o = {acc[i][j][0] + bb, acc[i][j][1] + bb,
                  acc[i][j][2] + bb, acc[i][j][3] + bb};
      *(float4*)&Cf[(size_t)col * 4096 + row] = o;
    }
}

// ---------------------------------------------------------------------------
// Flash attention half-range pass (unchanged from R9-passing).
// 512 threads = 8 waves, q-tile 256. grid (S/256, 8, 4): z = jh*2 + b.
// K/V double-buffered; one waitcnt(0)+barrier per j-iter.
// Writes UNNORMALIZED partial O^T (bf16, [jh][B][S][E]) + partial l (fp32).
// K/V LDS tiles XOR-chunk-swizzled: 16B chunk c of row r stored at c^(r&7).
// LDS: Kl 16K + Vl 16K + Pl 36K = 68 KB -> 2 blocks/CU.
// ---------------------------------------------------------------------------
__global__ __launch_bounds__(512, 4) void attn128(
    const uint16_t* __restrict__ Q, const uint16_t* __restrict__ K,
    const uint16_t* __restrict__ Vt, uint16_t* __restrict__ Ap,
    float* __restrict__ Lp) {
  constexpr int S = 4096, E = 512;
  const int b = blockIdx.z & 1, jh = blockIdx.z >> 1;
  const int h = blockIdx.y;
  const int i0 = blockIdx.x * 256;
  const int t = threadIdx.x, lane = t & 63, wave = t >> 6;
  const int lr = lane & 15, lq = lane >> 4;
  const size_t qkB = (size_t)b * S * E;
  const size_t vB = (size_t)b * E * S;
  __shared__ uint16_t Kl[2][64 * 64];     // [buf][j][d], chunk-swizzled rows
  __shared__ uint16_t Vl[2][64 * 64];     // [buf][d][j], chunk-swizzled rows
  __shared__ __bf16 Pl[8 * 2 * 16 * 72];  // [wave][g][i 16][j 64+8pad]

  const int qbase = i0 + wave * 32;
  bf16x8 qf[2][2];
  for (int g = 0; g < 2; ++g) {
    const size_t qo = qkB + (size_t)(qbase + g * 16 + lr) * E + h * 64 + lq * 8;
    qf[g][0] = *(const bf16x8*)&Q[qo];
    qf[g][1] = *(const bf16x8*)&Q[qo + 32];
  }
  f32x4 lsum[2] = {};
  f32x4 accOT[2][4] = {};
  const int swz = (lr & 7);
  const int srr = t >> 3, ssc = ((t & 7) ^ (srr & 7)) * 8;  // staging row/col

  const int jbeg = jh * (S / 2), jend = jbeg + S / 2;
  async16(&K[qkB + (size_t)(jbeg + srr) * E + h * 64 + ssc], &Kl[0][wave * 512]);
  async16(&Vt[vB + (size_t)(h * 64 + srr) * S + jbeg + ssc], &Vl[0][wave * 512]);
  __builtin_amdgcn_s_waitcnt(0);
  __syncthreads();

  int cur = 0;
  for (int j0 = jbeg; j0 < jend; j0 += 64) {
    if (j0 + 64 < jend) {
      async16(&K[qkB + (size_t)(j0 + 64 + srr) * E + h * 64 + ssc], &Kl[cur ^ 1][wave * 512]);
      async16(&Vt[vB + (size_t)(h * 64 + srr) * S + j0 + 64 + ssc], &Vl[cur ^ 1][wave * 512]);
    }
    const uint16_t* Kc = Kl[cur];
    const uint16_t* Vc = Vl[cur];
    f32x4 svt[2][4];
    for (int jn = 0; jn < 4; ++jn) {
      const int row = jn * 16 + lr;
      const int c0 = (lq ^ swz) * 8;
      bf16x8 ka0 = *(const bf16x8*)&Kc[row * 64 + c0];
      bf16x8 ka1 = *(const bf16x8*)&Kc[row * 64 + (c0 ^ 32)];
      for (int g = 0; g < 2; ++g) {
        f32x4 z = {0.f, 0.f, 0.f, 0.f};
        z = __builtin_amdgcn_mfma_f32_16x16x32_bf16(ka0, qf[g][0], z, 0, 0, 0);
        z = __builtin_amdgcn_mfma_f32_16x16x32_bf16(ka1, qf[g][1], z, 0, 0, 0);
        svt[g][jn] = z;
      }
    }
    for (int g = 0; g < 2; ++g) {
      __bf16* pr = &Pl[((wave * 2 + g) * 16 + lr) * 72];
      for (int jn = 0; jn < 4; ++jn) {
        f32x4 p;
        for (int r = 0; r < 4; ++r) p[r] = exp2f(svt[g][jn][r]);
        lsum[g] += p;
        bf16x4 pk;
        for (int r = 0; r < 4; ++r) pk[r] = (__bf16)p[r];
        *(bf16x4*)&pr[jn * 16 + lq * 4] = pk;
      }
    }
    bf16x8 pa[2][2];
    for (int g = 0; g < 2; ++g) {
      const __bf16* pr = &Pl[((wave * 2 + g) * 16 + lr) * 72];
      pa[g][0] = *(const bf16x8*)&pr[lq * 8];
      pa[g][1] = *(const bf16x8*)&pr[32 + lq * 8];
    }
    for (int dn = 0; dn < 4; ++dn) {
      const int row = dn * 16 + lr;
      const int c0 = (lq ^ swz) * 8;
      bf16x8 v0 = *(const bf16x8*)&Vc[row * 64 + c0];
      bf16x8 v1 = *(const bf16x8*)&Vc[row * 64 + (c0 ^ 32)];
      for (int g = 0; g < 2; ++g) {
        accOT[g][dn] = __builtin_amdgcn_mfma_f32_16x16x32_bf16(v0, pa[g][0], accOT[g][dn], 0, 0, 0);
        accOT[g][dn] = __builtin_amdgcn_mfma_f32_16x16x32_bf16(v1, pa[g][1], accOT[g][dn], 0, 0, 0);
      }
    }
    __builtin_amdgcn_s_waitcnt(0);
    __syncthreads();
    cur ^= 1;
  }
  uint16_t* Aph = Ap + (size_t)jh * 2 * S * E;
  float* Lph = Lp + ((size_t)(jh * 2 + b) * 8 + h) * S;
  for (int g = 0; g < 2; ++g) {
    float lt = (lsum[g][0] + lsum[g][1]) + (lsum[g][2] + lsum[g][3]);
    lt += __shfl_xor(lt, 16);
    lt += __shfl_xor(lt, 32);
    if (lane < 16) Lph[qbase + g * 16 + lr] = lt;
    const size_t row = qbase + g * 16 + lr;
    for (int dn = 0; dn < 4; ++dn) {
      u16x4 o;
      for (int r = 0; r < 4; ++r) o[r] = f2bf(accOT[g][dn][r]);
      *(u16x4*)&Aph[qkB + row * E + h * 64 + dn * 16 + lq * 4] = o;
    }
  }
}

// ---------------------------------------------------------------------------
extern "C" void kernel_launch(void* const* d_in, const int* in_sizes, int n_in,
                              void* d_out, int out_size, void* d_ws, size_t ws_size,
                              hipStream_t stream) {
  const float* x   = (const float*)d_in[0];
  const float* ctx = (const float*)d_in[1];
  const float* Wq  = (const float*)d_in[2];
  const float* bq  = (const float*)d_in[3];
  const float* Wk  = (const float*)d_in[4];
  const float* bk  = (const float*)d_in[5];
  const float* Wv  = (const float*)d_in[6];
  const float* bv  = (const float*)d_in[7];
  const float* Wo  = (const float*)d_in[8];
  const float* bo  = (const float*)d_in[9];
  float* out = (float*)d_out;

  const size_t SZ = (size_t)2 * 4096 * 512;
  uint16_t* xT = (uint16_t*)d_ws;
  uint16_t* cT = xT + SZ;
  uint16_t* Qb = cT + SZ;
  uint16_t* Kb = Qb + SZ;
  uint16_t* Vb = Kb + SZ;    // Vt layout [B][E][S]
  uint16_t* Wqb = Vb + SZ;
  uint16_t* Wkb = Wqb + 512 * 512;
  uint16_t* Wvb = Wkb + 512 * 512;
  uint16_t* Wob = Wvb + 512 * 512;
  uint16_t* Ap  = Wob + 512 * 512;            // partial O, [2][B][S][E] bf16
  float*    Lp  = (float*)(Ap + 2 * SZ);      // partial l, [2][B][8][S] fp32
  const long long sIn = 4096LL * 512LL;
  const float slh = 0.125f * 1.44269504088896f;  // SCALE * log2(e)

  prep<<<dim3(64, 8, 5), 256, 0, stream>>>(x, ctx, Wq, Wk, Wv, Wo,
                                           xT, cT, Wqb, Wkb, Wvb, Wob);
  // fused Q,K,V projections (m/n swapped for vector stores); Q pre-scaled
  QkvArgs qkv = {
      {Wqb, Wkb, cT}, {0, 0, sIn},          // A
      {xT, cT, Wvb}, {sIn, sIn, 0},         // B
      {Qb, Kb, Vb}, {sIn, sIn, sIn},        // C
      {bq, bk, bv},
      {slh, 1.f, 1.f},
      {512, 512, 4096},                      // ldC
      {5, 5, 2},                             // lx = log2(n-tiles)
      {1, 1, 0}};                            // brow
  gemm_qkv<<<dim3(128, 1, 6), 256, 0, stream>>>(qkv);
  attn128<<<dim3(16, 8, 4), 512, 0, stream>>>(Qb, Kb, Vb, Ap, Lp);
  // Y[c][s] = sum_e ((Ap0+Ap1)/(l0+l1))[s][e] * Wo[c][e] + bo[c]
  gemm_out<<<dim3(8, 32, 2), 256, 0, stream>>>(Ap, Lp, Wob, out, bo);
}